// Round 1
// baseline (663.090 us; speedup 1.0000x reference)
//
#include <hip/hip_runtime.h>
#include <math.h>

#define D 256
#define BLOCK 256
#define NWAVES 4

// One block per segment. batch[] is sorted, so segment s occupies the
// contiguous row range [lower_bound(batch,s), lower_bound(batch,s+1)).
// Each wave owns one row per loop iteration: 64 lanes x float4 = 1KB row,
// coalesced 16B/lane. Score via in-wave shuffle butterfly; online-softmax
// (running m,l + rescale) so x is read from HBM exactly ONCE.
__global__ __launch_bounds__(BLOCK) void niche_attn_kernel(
    const float* __restrict__ x,
    const float* __restrict__ w,
    const float* __restrict__ bptr,
    const int*   __restrict__ batch,
    float*       __restrict__ out,
    int N)
{
    const int seg  = blockIdx.x;
    const int tid  = threadIdx.x;
    const int wave = tid >> 6;
    const int lane = tid & 63;

    __shared__ int   s_bounds[2];
    __shared__ float s_m[NWAVES];
    __shared__ float s_l[NWAVES];
    __shared__ float s_acc[NWAVES][D];   // 4 KB

    // Per-block binary search for segment boundaries.
    if (tid < 2) {
        const int target = seg + tid;
        int lo = 0, hi = N;
        while (lo < hi) {
            const int mid = (lo + hi) >> 1;
            if (batch[mid] < target) lo = mid + 1; else hi = mid;
        }
        s_bounds[tid] = lo;
    }
    __syncthreads();
    const int row_start = s_bounds[0];
    const int row_end   = s_bounds[1];

    float* outp = out + (size_t)seg * D;

    if (row_end <= row_start) {       // empty segment -> zeros (block-uniform)
        outp[tid] = 0.f;
        return;
    }

    const int    col  = lane << 2;                 // this lane's 4 columns
    const float4 w4   = *(const float4*)(w + col);
    const float  bias = *bptr;

    float  m = -INFINITY;
    float  l = 0.f;
    float4 acc = make_float4(0.f, 0.f, 0.f, 0.f);

    for (int row = row_start + wave; row < row_end; row += NWAVES) {
        const float4 x4 = *(const float4*)(x + (size_t)row * D + col);
        // partial dot for this lane's 4 columns
        float s = x4.x * w4.x + x4.y * w4.y + x4.z * w4.z + x4.w * w4.w;
        // wave-wide butterfly reduce (all 64 lanes end with the row score)
#pragma unroll
        for (int off = 32; off > 0; off >>= 1)
            s += __shfl_xor(s, off, 64);
        s += bias;
        // online softmax update (wave-uniform branch)
        if (s > m) {
            const float alpha = __expf(m - s);     // m=-inf on first row -> 0
            l *= alpha;
            acc.x *= alpha; acc.y *= alpha; acc.z *= alpha; acc.w *= alpha;
            m = s;
        }
        const float p = __expf(s - m);
        l += p;
        acc.x = fmaf(x4.x, p, acc.x);
        acc.y = fmaf(x4.y, p, acc.y);
        acc.z = fmaf(x4.z, p, acc.z);
        acc.w = fmaf(x4.w, p, acc.w);
    }

    // Merge the 4 waves' online-softmax states.
    if (lane == 0) { s_m[wave] = m; s_l[wave] = l; }
    __syncthreads();

    const float M = fmaxf(fmaxf(s_m[0], s_m[1]), fmaxf(s_m[2], s_m[3]));
    float L = 0.f;
#pragma unroll
    for (int wv = 0; wv < NWAVES; ++wv)
        L += s_l[wv] * __expf(s_m[wv] - M);        // exp(-inf)=0 for idle waves

    const float scale = __expf(m - M);             // 0 for waves with no rows
    s_acc[wave][col + 0] = acc.x * scale;
    s_acc[wave][col + 1] = acc.y * scale;
    s_acc[wave][col + 2] = acc.z * scale;
    s_acc[wave][col + 3] = acc.w * scale;
    __syncthreads();

    const float invL = 1.f / L;
    const float v = (s_acc[0][tid] + s_acc[1][tid]) + (s_acc[2][tid] + s_acc[3][tid]);
    outp[tid] = v * invL;
}

extern "C" void kernel_launch(void* const* d_in, const int* in_sizes, int n_in,
                              void* d_out, int out_size, void* d_ws, size_t ws_size,
                              hipStream_t stream)
{
    const float* x     = (const float*)d_in[0];
    const float* w     = (const float*)d_in[1];
    const float* b     = (const float*)d_in[2];
    const int*   batch = (const int*)d_in[3];
    float*       out   = (float*)d_out;

    const int N = in_sizes[3];          // batch[] length
    const int B = out_size / D;         // num_segments (4096)

    niche_attn_kernel<<<B, BLOCK, 0, stream>>>(x, w, b, batch, out, N);
}

// Round 2
// 661.769 us; speedup vs baseline: 1.0020x; 1.0020x over previous
//
#include <hip/hip_runtime.h>
#include <math.h>

#define D 256
#define BLOCK 256
#define NWAVES 4
#define R 4              // rows per wave per iteration (4 KB in flight/wave + 4 KB prefetch)

// One block per segment (batch[] sorted -> contiguous row range via binary search).
// Each wave processes R consecutive rows per iteration: 64 lanes x float4 = full
// 1 KB row, coalesced. R independent shuffle butterflies hide DS latency; one
// branchless online-softmax rescale per chunk; one-chunk-ahead clamped prefetch
// keeps 8 row-loads in flight per wave. x is read from HBM exactly once.
__global__ __launch_bounds__(BLOCK) void niche_attn_kernel(
    const float* __restrict__ x,
    const float* __restrict__ w,
    const float* __restrict__ bptr,
    const int*   __restrict__ batch,
    float*       __restrict__ out,
    int N)
{
    const int seg  = blockIdx.x;
    const int tid  = threadIdx.x;
    const int wave = tid >> 6;
    const int lane = tid & 63;

    __shared__ int   s_bounds[2];
    __shared__ float s_m[NWAVES];
    __shared__ float s_l[NWAVES];
    __shared__ float s_acc[NWAVES][D];   // 4 KB

    // Segment boundaries: lower_bound(batch, seg) / lower_bound(batch, seg+1)
    if (tid < 2) {
        const int target = seg + tid;
        int lo = 0, hi = N;
        while (lo < hi) {
            const int mid = (lo + hi) >> 1;
            if (batch[mid] < target) lo = mid + 1; else hi = mid;
        }
        s_bounds[tid] = lo;
    }
    __syncthreads();
    const int row_start = s_bounds[0];
    const int row_end   = s_bounds[1];

    float* outp = out + (size_t)seg * D;

    if (row_end <= row_start) {          // empty segment -> zeros (block-uniform)
        outp[tid] = 0.f;
        return;
    }

    const int    col  = lane << 2;       // this lane's 4 columns
    const float4 w4   = *(const float4*)(w + col);
    const float  bias = *bptr;

    float  m = -INFINITY;
    float  l = 0.f;
    float4 acc = make_float4(0.f, 0.f, 0.f, 0.f);

    const int step = NWAVES * R;
    int row = row_start + wave * R;      // this wave's first chunk

    float4 cx[R];
    if (row < row_end) {
#pragma unroll
        for (int i = 0; i < R; ++i) {
            int r = row + i; r = (r < row_end) ? r : (row_end - 1);   // clamp: safe, L1-hit
            cx[i] = *(const float4*)(x + (size_t)r * D + col);
        }
    }

    while (row < row_end) {
        const int nrow = row + step;
        // Unconditional clamped prefetch of the next chunk (branch-free so it
        // issues before the compute chain; clamped dup rows are L1 hits).
        float4 nx[R];
#pragma unroll
        for (int i = 0; i < R; ++i) {
            int r = nrow + i; r = (r < row_end) ? r : (row_end - 1);
            nx[i] = *(const float4*)(x + (size_t)r * D + col);
        }

        // R independent partial dots + interleaved butterflies (latency hidden)
        float s[R];
#pragma unroll
        for (int i = 0; i < R; ++i)
            s[i] = cx[i].x * w4.x + cx[i].y * w4.y + cx[i].z * w4.z + cx[i].w * w4.w;
#pragma unroll
        for (int off = 32; off > 0; off >>= 1) {
#pragma unroll
            for (int i = 0; i < R; ++i)
                s[i] += __shfl_xor(s[i], off, 64);
        }
#pragma unroll
        for (int i = 0; i < R; ++i)
            s[i] = (row + i < row_end) ? (s[i] + bias) : -INFINITY;  // tail rows -> p=0

        // Branchless online-softmax update, once per chunk.
        // First iter: m=-inf -> alpha=exp(-inf)=0; s[0] always finite in-loop.
        const float cmax = fmaxf(fmaxf(s[0], s[1]), fmaxf(s[2], s[3]));
        const float newm = fmaxf(m, cmax);
        const float alpha = __expf(m - newm);
        float p[R];
#pragma unroll
        for (int i = 0; i < R; ++i)
            p[i] = __expf(s[i] - newm);

        l = l * alpha + ((p[0] + p[1]) + (p[2] + p[3]));
        acc.x *= alpha; acc.y *= alpha; acc.z *= alpha; acc.w *= alpha;
#pragma unroll
        for (int i = 0; i < R; ++i) {
            acc.x = fmaf(cx[i].x, p[i], acc.x);
            acc.y = fmaf(cx[i].y, p[i], acc.y);
            acc.z = fmaf(cx[i].z, p[i], acc.z);
            acc.w = fmaf(cx[i].w, p[i], acc.w);
        }
        m = newm;

#pragma unroll
        for (int i = 0; i < R; ++i) cx[i] = nx[i];
        row = nrow;
    }

    // Merge the 4 waves' online-softmax states.
    if (lane == 0) { s_m[wave] = m; s_l[wave] = l; }
    __syncthreads();

    const float M = fmaxf(fmaxf(s_m[0], s_m[1]), fmaxf(s_m[2], s_m[3]));
    float L = 0.f;
#pragma unroll
    for (int wv = 0; wv < NWAVES; ++wv)
        L += s_l[wv] * __expf(s_m[wv] - M);        // idle wave: 0 * exp(-inf) = 0

    const float scale = __expf(m - M);             // 0 for waves with no rows
    s_acc[wave][col + 0] = acc.x * scale;
    s_acc[wave][col + 1] = acc.y * scale;
    s_acc[wave][col + 2] = acc.z * scale;
    s_acc[wave][col + 3] = acc.w * scale;
    __syncthreads();

    const float invL = 1.f / L;
    const float v = (s_acc[0][tid] + s_acc[1][tid]) + (s_acc[2][tid] + s_acc[3][tid]);
    outp[tid] = v * invL;
}

extern "C" void kernel_launch(void* const* d_in, const int* in_sizes, int n_in,
                              void* d_out, int out_size, void* d_ws, size_t ws_size,
                              hipStream_t stream)
{
    const float* x     = (const float*)d_in[0];
    const float* w     = (const float*)d_in[1];
    const float* b     = (const float*)d_in[2];
    const int*   batch = (const int*)d_in[3];
    float*       out   = (float*)d_out;

    const int N = in_sizes[3];          // batch[] length
    const int B = out_size / D;         // num_segments (4096)

    niche_attn_kernel<<<B, BLOCK, 0, stream>>>(x, w, b, batch, out, N);
}